// Round 9
// baseline (65.280 us; speedup 1.0000x reference)
//
#include <hip/hip_runtime.h>
#include <math.h>

#define B_SZ 1024
#define D_SZ 2048
#define MARGIN 0.3f

typedef _Float16 f16x8 __attribute__((ext_vector_type(8)));
typedef float f32x16 __attribute__((ext_vector_type(16)));

union FragU { uint4 u; f16x8 v; };
union H4 { _Float16 h[4]; uint2 u; };

#define AS1 __attribute__((address_space(1)))
#define AS3 __attribute__((address_space(3)))

// ws layout (fast path):
// [0, 4MB)       Fh : fp16, MFMA-fragment-order granules
// [4MB, +64KB)   sqpart[16][1024] f32
// then hp / hn / flags (1024 ints each)

// ---------------- fused prep: fp16 swizzle + sq partials + init ----------------

__global__ __launch_bounds__(256) void prep_kernel(const float* __restrict__ F,
                                                   _Float16* __restrict__ Fh,
                                                   float* __restrict__ sqpart,
                                                   int* __restrict__ hp,
                                                   int* __restrict__ hn,
                                                   int* __restrict__ flags) {
    __shared__ _Float16 slab[64][136];   // 64 rows x 128 cols, +8 pad
    __shared__ float part[64];

    const int b = blockIdx.x;            // 256 blocks
    const int i = b >> 4;                // 64-row group
    const int kseg = b & 15;             // 128-col segment
    const int t = threadIdx.x;
    const int lane = t & 63;
    const int w = t >> 6;

    const int idx = b * 256 + t;
    if (idx < 1024) {
        hp[idx] = 0;                     // 0.0f bits; real dists are > 0
        hn[idx] = 0x7F800000;            // +inf
        flags[idx] = 0;
    }

#pragma unroll
    for (int q = 0; q < 8; ++q) {
        const int rl = q * 8 + (t >> 5);
        const int c4 = (t & 31) * 4;
        const float4 v = *(const float4*)(F + (size_t)(i * 64 + rl) * D_SZ +
                                          kseg * 128 + c4);
        float s = v.x * v.x + v.y * v.y + v.z * v.z + v.w * v.w;
#pragma unroll
        for (int mask = 1; mask < 32; mask <<= 1) s += __shfl_xor(s, mask);
        if ((t & 31) == 0) part[rl] = s;
        H4 p;
        p.h[0] = (_Float16)v.x; p.h[1] = (_Float16)v.y;
        p.h[2] = (_Float16)v.z; p.h[3] = (_Float16)v.w;
        *(uint2*)&slab[rl][c4] = p.u;
    }
    __syncthreads();

    if (t < 64) sqpart[kseg * 1024 + i * 64 + t] = part[t];

#pragma unroll
    for (int q2 = 0; q2 < 4; ++q2) {
        const int u = w * 4 + q2;
        const int kb = u >> 1;
        const int rg = u & 1;
        const uint4 d = *(const uint4*)&slab[rg * 32 + (lane & 31)]
                                          [kb * 16 + (lane >> 5) * 8];
        const size_t g = (size_t)((i * 128 + kseg * 8 + kb) * 2 + rg);
        *(uint4*)((char*)Fh + g * 1024 + (size_t)lane * 16) = d;
    }
}

// ---------------- dist: DMA-ring fp16 MFMA, 64x32 tiles, 512 blocks ----------
// IDENTICAL to round-8 kernel. Launched 3x this round as an in-band timer:
// all output is via idempotent atomics, so extra launches change nothing.

#define WAVE_STAGE (3 * 6144)

__global__ __launch_bounds__(256) void dist_f16_kernel(
    const _Float16* __restrict__ Fh, const int* __restrict__ labels,
    const float* __restrict__ sqpart, int* __restrict__ hp,
    int* __restrict__ hn, int* __restrict__ flags) {
    __shared__ __align__(16) char stage[4 * WAVE_STAGE];   // 72KB; reused for combine
    __shared__ int labR[64], labC[32];
    __shared__ float sqR[64], sqC[32];

    const int t = threadIdx.x;
    const int lane = t & 63;
    const int w = t >> 6;   // wave id = K-quarter

    const int xcd = blockIdx.x & 7;
    const int cidx = blockIdx.x >> 3;          // 0..63
    const int bi = (xcd >> 1) * 4 + (cidx >> 4);   // 0..15 (64-row group)
    const int bj = (xcd & 1) * 16 + (cidx & 15);   // 0..31 (32-col group)
    const int rowBase = bi * 64, colBase = bj * 32;

    if (t < 64) {
        const int row = rowBase + t;
        float s = 0.f;
#pragma unroll
        for (int p = 0; p < 16; ++p) s += sqpart[p * 1024 + row];
        sqR[t] = s;
        labR[t] = labels[row];
    } else if (t < 96) {
        const int e = t - 64;
        const int row = colBase + e;
        float s = 0.f;
#pragma unroll
        for (int p = 0; p < 16; ++p) s += sqpart[p * 1024 + row];
        sqC[e] = s;
        labC[e] = labels[row];
    }
    __syncthreads();
    asm volatile("s_waitcnt vmcnt(0)" ::: "memory");

    const char* __restrict__ FhB = (const char*)Fh;
    char* wbase = stage + w * WAVE_STAGE;
    const char* rbase = wbase + lane * 16;

    f32x16 acc[2];
#pragma unroll
    for (int a = 0; a < 2; ++a)
#pragma unroll
        for (int e = 0; e < 16; ++e) acc[a][e] = 0.f;

    auto ISSUE = [&](int s, int b) {
        const int kb16 = w * 32 + s * 2;
        const size_t aOff = (size_t)((bi * 128 + kb16) * 2) * 1024 + (size_t)lane * 16;
        const size_t bOff = (size_t)(((bj >> 1) * 128 + kb16) * 2 + (bj & 1)) * 1024 +
                            (size_t)lane * 16;
        char* dA = wbase + b * 6144;
#pragma unroll
        for (int c = 0; c < 4; ++c)
            __builtin_amdgcn_global_load_lds(
                (const AS1 void*)(FhB + aOff + c * 1024),
                (AS3 void*)(dA + c * 1024), 16, 0, 0);
        __builtin_amdgcn_global_load_lds(
            (const AS1 void*)(FhB + bOff),
            (AS3 void*)(dA + 4096), 16, 0, 0);
        __builtin_amdgcn_global_load_lds(
            (const AS1 void*)(FhB + bOff + 2048),
            (AS3 void*)(dA + 5120), 16, 0, 0);
    };
    auto COMPUTE = [&](int b) {
        const char* rb = rbase + b * 6144;
#pragma unroll
        for (int kl = 0; kl < 2; ++kl) {
            FragU a0, a1, v0;
            a0.u = *(const uint4*)(rb + (kl * 2 + 0) * 1024);
            a1.u = *(const uint4*)(rb + (kl * 2 + 1) * 1024);
            v0.u = *(const uint4*)(rb + 4096 + kl * 1024);
            acc[0] = __builtin_amdgcn_mfma_f32_32x32x16_f16(a0.v, v0.v, acc[0], 0, 0, 0);
            acc[1] = __builtin_amdgcn_mfma_f32_32x32x16_f16(a1.v, v0.v, acc[1], 0, 0, 0);
        }
    };

#define WAIT12 asm volatile("s_waitcnt vmcnt(12)" ::: "memory"); __builtin_amdgcn_sched_barrier(0)
#define WAIT6  asm volatile("s_waitcnt vmcnt(6)"  ::: "memory"); __builtin_amdgcn_sched_barrier(0)
#define WAIT0  asm volatile("s_waitcnt vmcnt(0)"  ::: "memory"); __builtin_amdgcn_sched_barrier(0)

    ISSUE(0, 0);
    ISSUE(1, 1);
    for (int s3 = 0; s3 < 12; s3 += 3) {   // s = 0..11
        ISSUE(s3 + 2, 2); WAIT12; COMPUTE(0);
        ISSUE(s3 + 3, 0); WAIT12; COMPUTE(1);
        ISSUE(s3 + 4, 1); WAIT12; COMPUTE(2);
    }
    ISSUE(14, 2); WAIT12; COMPUTE(0);      // s = 12
    ISSUE(15, 0); WAIT12; COMPUTE(1);      // s = 13
    WAIT6;  COMPUTE(2);                    // s = 14
    WAIT0;  COMPUTE(0);                    // s = 15

#undef WAIT12
#undef WAIT6
#undef WAIT0

    __syncthreads();

    char* cb = stage;
#pragma unroll
    for (int fr = 0; fr < 2; ++fr)
#pragma unroll
        for (int g = 0; g < 4; ++g) {
            float4 v;
            v.x = acc[fr][g * 4 + 0];
            v.y = acc[fr][g * 4 + 1];
            v.z = acc[fr][g * 4 + 2];
            v.w = acc[fr][g * 4 + 3];
            *(float4*)(cb + (size_t)(w * 8192) +
                       (size_t)((fr * 4 + g) * 64 + lane) * 16) = v;
        }
    __syncthreads();

    if (w < 2) {
        const int fr = w;
        float cS[16];
#pragma unroll
        for (int e = 0; e < 16; ++e) cS[e] = 0.f;
#pragma unroll
        for (int wp = 0; wp < 4; ++wp)
#pragma unroll
            for (int g = 0; g < 4; ++g) {
                float4 v = *(const float4*)(cb + (size_t)(wp * 8192) +
                                            (size_t)((fr * 4 + g) * 64 + lane) * 16);
                cS[g * 4 + 0] += v.x;
                cS[g * 4 + 1] += v.y;
                cS[g * 4 + 2] += v.z;
                cS[g * 4 + 3] += v.w;
            }

        const float BIG = 1e38f;
        const int h = lane >> 5;
        const int colL = lane & 31;
        const int j = colBase + colL;
        const int lj = labC[colL];
        const float sqj = sqC[colL];
#pragma unroll
        for (int k = 0; k < 16; ++k) {
            const int rowL = fr * 32 + (k & 3) + 8 * (k >> 2) + 4 * h;
            const int i = rowBase + rowL;
            const float d2 = sqR[rowL] + sqj - 2.f * cS[k];
            const float d = sqrtf(fmaxf(d2, 1e-12f));
            const bool eq = (labR[rowL] == lj);
            const bool isPos = eq && (i != j);
            float pv = isPos ? d : -BIG;
            float nv = eq ? BIG : d;
            int pf = (isPos ? 1 : 0) | (eq ? 0 : 2);
#pragma unroll
            for (int mask = 1; mask < 32; mask <<= 1) {
                pv = fmaxf(pv, __shfl_xor(pv, mask));
                nv = fminf(nv, __shfl_xor(nv, mask));
                pf |= __shfl_xor(pf, mask);
            }
            if (colL == 0) {
                if (pf & 1) atomicMax(&hp[i], __float_as_int(pv));
                if (pf & 2) atomicMin(&hn[i], __float_as_int(nv));
                if (pf) atomicOr(&flags[i], pf);
            }
        }
    }
}

// ---------------- final ----------------

__global__ __launch_bounds__(1024) void final_kernel(const int* __restrict__ hp,
                                                     const int* __restrict__ hn,
                                                     const int* __restrict__ flags,
                                                     float* __restrict__ out) {
    __shared__ float ssum[16];
    __shared__ int svalid[16], sact[16];
    const int t = threadIdx.x;
    const float hpv = __int_as_float(hp[t]);
    const float hnv = __int_as_float(hn[t]);
    const int f = flags[t];
    const bool valid = (f == 3);
    float pr = fmaxf(hpv - hnv + MARGIN, 0.f);
    if (!valid) pr = 0.f;
    int act = (valid && pr > 0.f) ? 1 : 0;
    int vld = valid ? 1 : 0;
    float s = pr;
    for (int off = 32; off; off >>= 1) {
        s += __shfl_down(s, off);
        act += __shfl_down(act, off);
        vld += __shfl_down(vld, off);
    }
    if ((t & 63) == 0) {
        ssum[t >> 6] = s;
        svalid[t >> 6] = vld;
        sact[t >> 6] = act;
    }
    __syncthreads();
    if (t == 0) {
        float tot = 0.f;
        int nv = 0, na = 0;
#pragma unroll
        for (int i = 0; i < 16; ++i) {
            tot += ssum[i];
            nv += svalid[i];
            na += sact[i];
        }
        out[0] = tot / (float)(nv > 1 ? nv : 1);
        out[1] = (float)na;
    }
}

// ---------------- fallback path: fp32 vector ----------------

#define BM 64
#define BN 64
#define BK 32

__global__ __launch_bounds__(256) void sq_kernel(const float* __restrict__ F,
                                                 float* __restrict__ sq) {
    int row = blockIdx.x;
    const float4* r4 = (const float4*)(F + (size_t)row * D_SZ);
    int t = threadIdx.x;
    float s = 0.f;
#pragma unroll
    for (int q = 0; q < 2; ++q) {
        float4 v = r4[t + q * 256];
        s += v.x * v.x + v.y * v.y + v.z * v.z + v.w * v.w;
    }
    for (int off = 32; off; off >>= 1) s += __shfl_down(s, off);
    __shared__ float wsum[4];
    if ((t & 63) == 0) wsum[t >> 6] = s;
    __syncthreads();
    if (t == 0) sq[row] = wsum[0] + wsum[1] + wsum[2] + wsum[3];
}

__global__ __launch_bounds__(256) void init_kernel(int* __restrict__ hp,
                                                   int* __restrict__ hn,
                                                   int* __restrict__ flags) {
    int i = blockIdx.x * 256 + threadIdx.x;
    hp[i] = 0;
    hn[i] = 0x7F800000;
    flags[i] = 0;
}

__global__ __launch_bounds__(256) void dist_f32_kernel(
    const float* __restrict__ F, const int* __restrict__ labels,
    const float* __restrict__ sq, int* __restrict__ hp, int* __restrict__ hn,
    int* __restrict__ flags) {
    __shared__ float As[BK][BM];
    __shared__ float Bs[BK][BN];
    __shared__ int labR[BM], labC[BN];
    __shared__ float sqR[BM], sqC[BN];

    const int rowBase = blockIdx.y * BM;
    const int colBase = blockIdx.x * BN;
    const int t = threadIdx.x;
    const int tx = t & 15;
    const int ty = t >> 4;

    if (t < 64) {
        labR[t] = labels[rowBase + t];
        sqR[t] = sq[rowBase + t];
    } else if (t < 128) {
        int u = t - 64;
        labC[u] = labels[colBase + u];
        sqC[u] = sq[colBase + u];
    }

    float acc[4][4] = {{0.f}};
    const int m = t & 63;
    const int q = t >> 6;
    const float* aRow = F + (size_t)(rowBase + m) * D_SZ + q * 8;
    const float* bRow = F + (size_t)(colBase + m) * D_SZ + q * 8;

    for (int k0 = 0; k0 < D_SZ; k0 += BK) {
        float4 a0 = *(const float4*)(aRow + k0);
        float4 a1 = *(const float4*)(aRow + k0 + 4);
        float4 b0 = *(const float4*)(bRow + k0);
        float4 b1 = *(const float4*)(bRow + k0 + 4);
        __syncthreads();
        int kb = q * 8;
        As[kb + 0][m] = a0.x; As[kb + 1][m] = a0.y;
        As[kb + 2][m] = a0.z; As[kb + 3][m] = a0.w;
        As[kb + 4][m] = a1.x; As[kb + 5][m] = a1.y;
        As[kb + 6][m] = a1.z; As[kb + 7][m] = a1.w;
        Bs[kb + 0][m] = b0.x; Bs[kb + 1][m] = b0.y;
        Bs[kb + 2][m] = b0.z; Bs[kb + 3][m] = b0.w;
        Bs[kb + 4][m] = b1.x; Bs[kb + 5][m] = b1.y;
        Bs[kb + 6][m] = b1.z; Bs[kb + 7][m] = b1.w;
        __syncthreads();
#pragma unroll
        for (int kk = 0; kk < BK; ++kk) {
            float4 a = *(const float4*)&As[kk][ty * 4];
            float4 b = *(const float4*)&Bs[kk][tx * 4];
            acc[0][0] += a.x * b.x; acc[0][1] += a.x * b.y;
            acc[0][2] += a.x * b.z; acc[0][3] += a.x * b.w;
            acc[1][0] += a.y * b.x; acc[1][1] += a.y * b.y;
            acc[1][2] += a.y * b.z; acc[1][3] += a.y * b.w;
            acc[2][0] += a.z * b.x; acc[2][1] += a.z * b.y;
            acc[2][2] += a.z * b.z; acc[2][3] += a.z * b.w;
            acc[3][0] += a.w * b.x; acc[3][1] += a.w * b.y;
            acc[3][2] += a.w * b.z; acc[3][3] += a.w * b.w;
        }
    }

    float mp[4], mn[4];
    int pf[4];
#pragma unroll
    for (int rr = 0; rr < 4; ++rr) {
        const int i = rowBase + ty * 4 + rr;
        const int li = labR[ty * 4 + rr];
        const float si = sqR[ty * 4 + rr];
        mp[rr] = -3.4e38f;
        mn[rr] = 3.4e38f;
        pf[rr] = 0;
#pragma unroll
        for (int c = 0; c < 4; ++c) {
            const int j = colBase + tx * 4 + c;
            const float d2 = si + sqC[tx * 4 + c] - 2.f * acc[rr][c];
            const float dist = sqrtf(fmaxf(d2, 1e-12f));
            const bool eq = (li == labC[tx * 4 + c]);
            if (eq && (i != j)) {
                mp[rr] = fmaxf(mp[rr], dist);
                pf[rr] |= 1;
            }
            if (!eq) {
                mn[rr] = fminf(mn[rr], dist);
                pf[rr] |= 2;
            }
        }
    }
#pragma unroll
    for (int mask = 1; mask < 16; mask <<= 1)
#pragma unroll
        for (int rr = 0; rr < 4; ++rr) {
            mp[rr] = fmaxf(mp[rr], __shfl_xor(mp[rr], mask));
            mn[rr] = fminf(mn[rr], __shfl_xor(mn[rr], mask));
            pf[rr] |= __shfl_xor(pf[rr], mask);
        }
    if (tx == 0) {
#pragma unroll
        for (int rr = 0; rr < 4; ++rr) {
            const int i = rowBase + ty * 4 + rr;
            if (pf[rr] & 1) atomicMax(&hp[i], __float_as_int(mp[rr]));
            if (pf[rr] & 2) atomicMin(&hn[i], __float_as_int(mn[rr]));
            if (pf[rr]) atomicOr(&flags[i], pf[rr]);
        }
    }
}

// ---------------- launch ----------------

extern "C" void kernel_launch(void* const* d_in, const int* in_sizes, int n_in,
                              void* d_out, int out_size, void* d_ws, size_t ws_size,
                              hipStream_t stream) {
    const float* F = (const float*)d_in[0];
    const int* labels = (const int*)d_in[1];
    float* out = (float*)d_out;
    char* ws = (char*)d_ws;

    const size_t FH = (size_t)B_SZ * D_SZ * 2;         // 4MB fp16 swizzled
    const size_t SQP = 16 * 1024 * sizeof(float);      // 64KB
    const size_t need = FH + SQP + 12 * 1024;

    if (ws_size >= need) {
        _Float16* Fh = (_Float16*)ws;
        float* sqpart = (float*)(ws + FH);
        char* tail = ws + FH + SQP;
        int* hp = (int*)tail;
        int* hn = (int*)(tail + 4096);
        int* flags = (int*)(tail + 8192);

        prep_kernel<<<256, 256, 0, stream>>>(F, Fh, sqpart, hp, hn, flags);
        // In-band timer: dist launched 3x (idempotent atomics -> identical output).
        // dur_us = base + 2*T_dist; see decision tree in analysis.
        dist_f16_kernel<<<512, 256, 0, stream>>>(Fh, labels, sqpart, hp, hn, flags);
        dist_f16_kernel<<<512, 256, 0, stream>>>(Fh, labels, sqpart, hp, hn, flags);
        dist_f16_kernel<<<512, 256, 0, stream>>>(Fh, labels, sqpart, hp, hn, flags);
        final_kernel<<<1, 1024, 0, stream>>>(hp, hn, flags, out);
    } else {
        float* sq = (float*)ws;
        int* hp = (int*)(ws + 4096);
        int* hn = (int*)(ws + 8192);
        int* flags = (int*)(ws + 12288);

        sq_kernel<<<B_SZ, 256, 0, stream>>>(F, sq);
        init_kernel<<<B_SZ / 256, 256, 0, stream>>>(hp, hn, flags);
        dim3 grid(B_SZ / BN, B_SZ / BM);
        dist_f32_kernel<<<grid, 256, 0, stream>>>(F, labels, sq, hp, hn, flags);
        final_kernel<<<1, 1024, 0, stream>>>(hp, hn, flags, out);
    }
}

// Round 10
// 32.485 us; speedup vs baseline: 2.0095x; 2.0095x over previous
//
#include <hip/hip_runtime.h>
#include <math.h>

#define B_SZ 1024
#define D_SZ 2048
#define MARGIN 0.3f

typedef _Float16 f16x8 __attribute__((ext_vector_type(8)));
typedef float f32x16 __attribute__((ext_vector_type(16)));

union FragU { uint4 u; f16x8 v; };
union H4 { _Float16 h[4]; uint2 u; };

#define AS1 __attribute__((address_space(1)))
#define AS3 __attribute__((address_space(3)))

// ws layout (fast path):
// [0, 4MB)       Fh : fp16, MFMA-fragment-order granules
//   granule g = ((i*128 + kb16)*2 + rg); byte addr g*1024 + lane*16
//   holds F[i*64 + rg*32 + (lane&31)][kb16*16 + (lane>>5)*8 .. +8]
// [4MB, +64KB)   sqpart[16][1024] f32
// then hp / hn / flags (1024 ints each)

// ---------------- fused prep: fp16 swizzle + sq partials + init ----------------

__global__ __launch_bounds__(256) void prep_kernel(const float* __restrict__ F,
                                                   _Float16* __restrict__ Fh,
                                                   float* __restrict__ sqpart,
                                                   int* __restrict__ hp,
                                                   int* __restrict__ hn,
                                                   int* __restrict__ flags) {
    __shared__ _Float16 slab[64][136];   // 64 rows x 128 cols, +8 pad
    __shared__ float part[64];

    const int b = blockIdx.x;            // 256 blocks
    const int i = b >> 4;                // 64-row group
    const int kseg = b & 15;             // 128-col segment
    const int t = threadIdx.x;
    const int lane = t & 63;
    const int w = t >> 6;

    const int idx = b * 256 + t;
    if (idx < 1024) {
        hp[idx] = 0;                     // 0.0f bits; real dists are > 0
        hn[idx] = 0x7F800000;            // +inf
        flags[idx] = 0;
    }

#pragma unroll
    for (int q = 0; q < 8; ++q) {
        const int rl = q * 8 + (t >> 5);
        const int c4 = (t & 31) * 4;
        const float4 v = *(const float4*)(F + (size_t)(i * 64 + rl) * D_SZ +
                                          kseg * 128 + c4);
        float s = v.x * v.x + v.y * v.y + v.z * v.z + v.w * v.w;
#pragma unroll
        for (int mask = 1; mask < 32; mask <<= 1) s += __shfl_xor(s, mask);
        if ((t & 31) == 0) part[rl] = s;
        H4 p;
        p.h[0] = (_Float16)v.x; p.h[1] = (_Float16)v.y;
        p.h[2] = (_Float16)v.z; p.h[3] = (_Float16)v.w;
        *(uint2*)&slab[rl][c4] = p.u;
    }
    __syncthreads();

    if (t < 64) sqpart[kseg * 1024 + i * 64 + t] = part[t];

#pragma unroll
    for (int q2 = 0; q2 < 4; ++q2) {
        const int u = w * 4 + q2;
        const int kb = u >> 1;
        const int rg = u & 1;
        const uint4 d = *(const uint4*)&slab[rg * 32 + (lane & 31)]
                                          [kb * 16 + (lane >> 5) * 8];
        const size_t g = (size_t)((i * 128 + kseg * 8 + kb) * 2 + rg);
        *(uint4*)((char*)Fh + g * 1024 + (size_t)lane * 16) = d;
    }
}

// ---------------- dist: deep-ring fp16 MFMA, 64x32 tiles, 512 blocks ---------
// 2 blocks/CU (72KB LDS). Per block: 4 waves, K-split 4 (K=512/wave),
// 32 sub-steps of K=16; ring 6 x 3KB per wave; lead = 5 substeps,
// steady-state wait = vmcnt(15) (oldest 3 loads of 18 in flight).

#define SUB_SZ 3072
#define WAVE_STAGE (6 * SUB_SZ)   // 18KB

__global__ __launch_bounds__(256) void dist_f16_kernel(
    const _Float16* __restrict__ Fh, const int* __restrict__ labels,
    const float* __restrict__ sqpart, int* __restrict__ hp,
    int* __restrict__ hn, int* __restrict__ flags) {
    __shared__ __align__(16) char stage[4 * WAVE_STAGE];   // 72KB; reused for combine
    __shared__ int labR[64], labC[32];
    __shared__ float sqR[64], sqC[32];

    const int t = threadIdx.x;
    const int lane = t & 63;
    const int w = t >> 6;   // wave id = K-quarter

    const int xcd = blockIdx.x & 7;
    const int cidx = blockIdx.x >> 3;          // 0..63
    const int bi = (xcd >> 1) * 4 + (cidx >> 4);   // 0..15 (64-row group)
    const int bj = (xcd & 1) * 16 + (cidx & 15);   // 0..31 (32-col group)
    const int rowBase = bi * 64, colBase = bj * 32;

    if (t < 64) {
        const int row = rowBase + t;
        float s = 0.f;
#pragma unroll
        for (int p = 0; p < 16; ++p) s += sqpart[p * 1024 + row];
        sqR[t] = s;
        labR[t] = labels[row];
    } else if (t < 96) {
        const int e = t - 64;
        const int row = colBase + e;
        float s = 0.f;
#pragma unroll
        for (int p = 0; p < 16; ++p) s += sqpart[p * 1024 + row];
        sqC[e] = s;
        labC[e] = labels[row];
    }
    __syncthreads();
    asm volatile("s_waitcnt vmcnt(0)" ::: "memory");   // clean vmcnt before counted loop

    const char* __restrict__ FhB = (const char*)Fh;
    char* wbase = stage + w * WAVE_STAGE;
    const char* rbase = wbase + lane * 16;

    f32x16 acc[2];
#pragma unroll
    for (int a = 0; a < 2; ++a)
#pragma unroll
        for (int e = 0; e < 16; ++e) acc[a][e] = 0.f;

    // One K=16 sub-step: A = 2 granules (rows 0-31, 32-63), B = 1 granule. 3KB.
    auto ISSUE = [&](int s, int b) {
        const int kb16 = w * 32 + s;
        const size_t aOff = (size_t)((bi * 128 + kb16) * 2) * 1024 + (size_t)lane * 16;
        const size_t bOff = (size_t)(((bj >> 1) * 128 + kb16) * 2 + (bj & 1)) * 1024 +
                            (size_t)lane * 16;
        char* dA = wbase + b * SUB_SZ;
        __builtin_amdgcn_global_load_lds((const AS1 void*)(FhB + aOff),
                                         (AS3 void*)(dA), 16, 0, 0);
        __builtin_amdgcn_global_load_lds((const AS1 void*)(FhB + aOff + 1024),
                                         (AS3 void*)(dA + 1024), 16, 0, 0);
        __builtin_amdgcn_global_load_lds((const AS1 void*)(FhB + bOff),
                                         (AS3 void*)(dA + 2048), 16, 0, 0);
    };
    // Consume one staged sub-step: 3 ds_read_b128 + 2 MFMA.
    auto COMPUTE = [&](int b) {
        const char* rb = rbase + b * SUB_SZ;
        FragU a0, a1, v0;
        a0.u = *(const uint4*)(rb);
        a1.u = *(const uint4*)(rb + 1024);
        v0.u = *(const uint4*)(rb + 2048);
        acc[0] = __builtin_amdgcn_mfma_f32_32x32x16_f16(a0.v, v0.v, acc[0], 0, 0, 0);
        acc[1] = __builtin_amdgcn_mfma_f32_32x32x16_f16(a1.v, v0.v, acc[1], 0, 0, 0);
    };

#define WAITN(n) asm volatile("s_waitcnt vmcnt(" #n ")" ::: "memory"); __builtin_amdgcn_sched_barrier(0)

    ISSUE(0, 0); ISSUE(1, 1); ISSUE(2, 2); ISSUE(3, 3); ISSUE(4, 4);
    for (int s6 = 0; s6 < 24; s6 += 6) {       // s = s6 .. s6+5
        ISSUE(s6 + 5, 5);  WAITN(15); COMPUTE(0);
        ISSUE(s6 + 6, 0);  WAITN(15); COMPUTE(1);
        ISSUE(s6 + 7, 1);  WAITN(15); COMPUTE(2);
        ISSUE(s6 + 8, 2);  WAITN(15); COMPUTE(3);
        ISSUE(s6 + 9, 3);  WAITN(15); COMPUTE(4);
        ISSUE(s6 + 10, 4); WAITN(15); COMPUTE(5);
    }
    ISSUE(29, 5); WAITN(15); COMPUTE(0);       // s = 24
    ISSUE(30, 0); WAITN(15); COMPUTE(1);       // s = 25
    ISSUE(31, 1); WAITN(15); COMPUTE(2);       // s = 26
    WAITN(12); COMPUTE(3);                     // s = 27
    WAITN(9);  COMPUTE(4);                     // s = 28
    WAITN(6);  COMPUTE(5);                     // s = 29
    WAITN(3);  COMPUTE(0);                     // s = 30
    WAITN(0);  COMPUTE(1);                     // s = 31

#undef WAITN

    __syncthreads();

    // Combine the 4 K-partials through LDS (32KB of the staging area).
    char* cb = stage;
#pragma unroll
    for (int fr = 0; fr < 2; ++fr)
#pragma unroll
        for (int g = 0; g < 4; ++g) {
            float4 v;
            v.x = acc[fr][g * 4 + 0];
            v.y = acc[fr][g * 4 + 1];
            v.z = acc[fr][g * 4 + 2];
            v.w = acc[fr][g * 4 + 3];
            *(float4*)(cb + (size_t)(w * 8192) +
                       (size_t)((fr * 4 + g) * 64 + lane) * 16) = v;
        }
    __syncthreads();

    // Waves 0,1 own frag fr = w: sum 4 partials, then epilogue.
    if (w < 2) {
        const int fr = w;
        float cS[16];
#pragma unroll
        for (int e = 0; e < 16; ++e) cS[e] = 0.f;
#pragma unroll
        for (int wp = 0; wp < 4; ++wp)
#pragma unroll
            for (int g = 0; g < 4; ++g) {
                float4 v = *(const float4*)(cb + (size_t)(wp * 8192) +
                                            (size_t)((fr * 4 + g) * 64 + lane) * 16);
                cS[g * 4 + 0] += v.x;
                cS[g * 4 + 1] += v.y;
                cS[g * 4 + 2] += v.z;
                cS[g * 4 + 3] += v.w;
            }

        const float BIG = 1e38f;
        const int h = lane >> 5;
        const int colL = lane & 31;
        const int j = colBase + colL;
        const int lj = labC[colL];
        const float sqj = sqC[colL];
#pragma unroll
        for (int k = 0; k < 16; ++k) {
            const int rowL = fr * 32 + (k & 3) + 8 * (k >> 2) + 4 * h;
            const int i = rowBase + rowL;
            const float d2 = sqR[rowL] + sqj - 2.f * cS[k];
            const float d = sqrtf(fmaxf(d2, 1e-12f));
            const bool eq = (labR[rowL] == lj);
            const bool isPos = eq && (i != j);
            float pv = isPos ? d : -BIG;
            float nv = eq ? BIG : d;
            int pf = (isPos ? 1 : 0) | (eq ? 0 : 2);
#pragma unroll
            for (int mask = 1; mask < 32; mask <<= 1) {
                pv = fmaxf(pv, __shfl_xor(pv, mask));
                nv = fminf(nv, __shfl_xor(nv, mask));
                pf |= __shfl_xor(pf, mask);
            }
            if (colL == 0) {
                if (pf & 1) atomicMax(&hp[i], __float_as_int(pv));
                if (pf & 2) atomicMin(&hn[i], __float_as_int(nv));
                if (pf) atomicOr(&flags[i], pf);
            }
        }
    }
}

// ---------------- final ----------------

__global__ __launch_bounds__(1024) void final_kernel(const int* __restrict__ hp,
                                                     const int* __restrict__ hn,
                                                     const int* __restrict__ flags,
                                                     float* __restrict__ out) {
    __shared__ float ssum[16];
    __shared__ int svalid[16], sact[16];
    const int t = threadIdx.x;
    const float hpv = __int_as_float(hp[t]);
    const float hnv = __int_as_float(hn[t]);
    const int f = flags[t];
    const bool valid = (f == 3);
    float pr = fmaxf(hpv - hnv + MARGIN, 0.f);
    if (!valid) pr = 0.f;
    int act = (valid && pr > 0.f) ? 1 : 0;
    int vld = valid ? 1 : 0;
    float s = pr;
    for (int off = 32; off; off >>= 1) {
        s += __shfl_down(s, off);
        act += __shfl_down(act, off);
        vld += __shfl_down(vld, off);
    }
    if ((t & 63) == 0) {
        ssum[t >> 6] = s;
        svalid[t >> 6] = vld;
        sact[t >> 6] = act;
    }
    __syncthreads();
    if (t == 0) {
        float tot = 0.f;
        int nv = 0, na = 0;
#pragma unroll
        for (int i = 0; i < 16; ++i) {
            tot += ssum[i];
            nv += svalid[i];
            na += sact[i];
        }
        out[0] = tot / (float)(nv > 1 ? nv : 1);
        out[1] = (float)na;
    }
}

// ---------------- fallback path: fp32 vector ----------------

#define BM 64
#define BN 64
#define BK 32

__global__ __launch_bounds__(256) void sq_kernel(const float* __restrict__ F,
                                                 float* __restrict__ sq) {
    int row = blockIdx.x;
    const float4* r4 = (const float4*)(F + (size_t)row * D_SZ);
    int t = threadIdx.x;
    float s = 0.f;
#pragma unroll
    for (int q = 0; q < 2; ++q) {
        float4 v = r4[t + q * 256];
        s += v.x * v.x + v.y * v.y + v.z * v.z + v.w * v.w;
    }
    for (int off = 32; off; off >>= 1) s += __shfl_down(s, off);
    __shared__ float wsum[4];
    if ((t & 63) == 0) wsum[t >> 6] = s;
    __syncthreads();
    if (t == 0) sq[row] = wsum[0] + wsum[1] + wsum[2] + wsum[3];
}

__global__ __launch_bounds__(256) void init_kernel(int* __restrict__ hp,
                                                   int* __restrict__ hn,
                                                   int* __restrict__ flags) {
    int i = blockIdx.x * 256 + threadIdx.x;
    hp[i] = 0;
    hn[i] = 0x7F800000;
    flags[i] = 0;
}

__global__ __launch_bounds__(256) void dist_f32_kernel(
    const float* __restrict__ F, const int* __restrict__ labels,
    const float* __restrict__ sq, int* __restrict__ hp, int* __restrict__ hn,
    int* __restrict__ flags) {
    __shared__ float As[BK][BM];
    __shared__ float Bs[BK][BN];
    __shared__ int labR[BM], labC[BN];
    __shared__ float sqR[BM], sqC[BN];

    const int rowBase = blockIdx.y * BM;
    const int colBase = blockIdx.x * BN;
    const int t = threadIdx.x;
    const int tx = t & 15;
    const int ty = t >> 4;

    if (t < 64) {
        labR[t] = labels[rowBase + t];
        sqR[t] = sq[rowBase + t];
    } else if (t < 128) {
        int u = t - 64;
        labC[u] = labels[colBase + u];
        sqC[u] = sq[colBase + u];
    }

    float acc[4][4] = {{0.f}};
    const int m = t & 63;
    const int q = t >> 6;
    const float* aRow = F + (size_t)(rowBase + m) * D_SZ + q * 8;
    const float* bRow = F + (size_t)(colBase + m) * D_SZ + q * 8;

    for (int k0 = 0; k0 < D_SZ; k0 += BK) {
        float4 a0 = *(const float4*)(aRow + k0);
        float4 a1 = *(const float4*)(aRow + k0 + 4);
        float4 b0 = *(const float4*)(bRow + k0);
        float4 b1 = *(const float4*)(bRow + k0 + 4);
        __syncthreads();
        int kb = q * 8;
        As[kb + 0][m] = a0.x; As[kb + 1][m] = a0.y;
        As[kb + 2][m] = a0.z; As[kb + 3][m] = a0.w;
        As[kb + 4][m] = a1.x; As[kb + 5][m] = a1.y;
        As[kb + 6][m] = a1.z; As[kb + 7][m] = a1.w;
        Bs[kb + 0][m] = b0.x; Bs[kb + 1][m] = b0.y;
        Bs[kb + 2][m] = b0.z; Bs[kb + 3][m] = b0.w;
        Bs[kb + 4][m] = b1.x; Bs[kb + 5][m] = b1.y;
        Bs[kb + 6][m] = b1.z; Bs[kb + 7][m] = b1.w;
        __syncthreads();
#pragma unroll
        for (int kk = 0; kk < BK; ++kk) {
            float4 a = *(const float4*)&As[kk][ty * 4];
            float4 b = *(const float4*)&Bs[kk][tx * 4];
            acc[0][0] += a.x * b.x; acc[0][1] += a.x * b.y;
            acc[0][2] += a.x * b.z; acc[0][3] += a.x * b.w;
            acc[1][0] += a.y * b.x; acc[1][1] += a.y * b.y;
            acc[1][2] += a.y * b.z; acc[1][3] += a.y * b.w;
            acc[2][0] += a.z * b.x; acc[2][1] += a.z * b.y;
            acc[2][2] += a.z * b.z; acc[2][3] += a.z * b.w;
            acc[3][0] += a.w * b.x; acc[3][1] += a.w * b.y;
            acc[3][2] += a.w * b.z; acc[3][3] += a.w * b.w;
        }
    }

    float mp[4], mn[4];
    int pf[4];
#pragma unroll
    for (int rr = 0; rr < 4; ++rr) {
        const int i = rowBase + ty * 4 + rr;
        const int li = labR[ty * 4 + rr];
        const float si = sqR[ty * 4 + rr];
        mp[rr] = -3.4e38f;
        mn[rr] = 3.4e38f;
        pf[rr] = 0;
#pragma unroll
        for (int c = 0; c < 4; ++c) {
            const int j = colBase + tx * 4 + c;
            const float d2 = si + sqC[tx * 4 + c] - 2.f * acc[rr][c];
            const float dist = sqrtf(fmaxf(d2, 1e-12f));
            const bool eq = (li == labC[tx * 4 + c]);
            if (eq && (i != j)) {
                mp[rr] = fmaxf(mp[rr], dist);
                pf[rr] |= 1;
            }
            if (!eq) {
                mn[rr] = fminf(mn[rr], dist);
                pf[rr] |= 2;
            }
        }
    }
#pragma unroll
    for (int mask = 1; mask < 16; mask <<= 1)
#pragma unroll
        for (int rr = 0; rr < 4; ++rr) {
            mp[rr] = fmaxf(mp[rr], __shfl_xor(mp[rr], mask));
            mn[rr] = fminf(mn[rr], __shfl_xor(mn[rr], mask));
            pf[rr] |= __shfl_xor(pf[rr], mask);
        }
    if (tx == 0) {
#pragma unroll
        for (int rr = 0; rr < 4; ++rr) {
            const int i = rowBase + ty * 4 + rr;
            if (pf[rr] & 1) atomicMax(&hp[i], __float_as_int(mp[rr]));
            if (pf[rr] & 2) atomicMin(&hn[i], __float_as_int(mn[rr]));
            if (pf[rr]) atomicOr(&flags[i], pf[rr]);
        }
    }
}

// ---------------- launch ----------------

extern "C" void kernel_launch(void* const* d_in, const int* in_sizes, int n_in,
                              void* d_out, int out_size, void* d_ws, size_t ws_size,
                              hipStream_t stream) {
    const float* F = (const float*)d_in[0];
    const int* labels = (const int*)d_in[1];
    float* out = (float*)d_out;
    char* ws = (char*)d_ws;

    const size_t FH = (size_t)B_SZ * D_SZ * 2;         // 4MB fp16 swizzled
    const size_t SQP = 16 * 1024 * sizeof(float);      // 64KB
    const size_t need = FH + SQP + 12 * 1024;

    if (ws_size >= need) {
        _Float16* Fh = (_Float16*)ws;
        float* sqpart = (float*)(ws + FH);
        char* tail = ws + FH + SQP;
        int* hp = (int*)tail;
        int* hn = (int*)(tail + 4096);
        int* flags = (int*)(tail + 8192);

        prep_kernel<<<256, 256, 0, stream>>>(F, Fh, sqpart, hp, hn, flags);
        dist_f16_kernel<<<512, 256, 0, stream>>>(Fh, labels, sqpart, hp, hn, flags);
        final_kernel<<<1, 1024, 0, stream>>>(hp, hn, flags, out);
    } else {
        float* sq = (float*)ws;
        int* hp = (int*)(ws + 4096);
        int* hn = (int*)(ws + 8192);
        int* flags = (int*)(ws + 12288);

        sq_kernel<<<B_SZ, 256, 0, stream>>>(F, sq);
        init_kernel<<<B_SZ / 256, 256, 0, stream>>>(hp, hn, flags);
        dim3 grid(B_SZ / BN, B_SZ / BM);
        dist_f32_kernel<<<grid, 256, 0, stream>>>(F, labels, sq, hp, hn, flags);
        final_kernel<<<1, 1024, 0, stream>>>(hp, hn, flags, out);
    }
}

// Round 11
// 32.283 us; speedup vs baseline: 2.0221x; 1.0063x over previous
//
#include <hip/hip_runtime.h>
#include <math.h>

#define B_SZ 1024
#define D_SZ 2048
#define MARGIN 0.3f

typedef _Float16 f16x8 __attribute__((ext_vector_type(8)));
typedef float f32x16 __attribute__((ext_vector_type(16)));

union FragU { uint4 u; f16x8 v; };
union H4 { _Float16 h[4]; uint2 u; };

// ws layout (fast path):
// [0, 4MB)       Fh : fp16, MFMA-fragment-order granules
//   granule g = ((i*128 + kb16)*2 + rg); byte addr g*1024 + lane*16
//   holds F[i*64 + rg*32 + (lane&31)][kb16*16 + (lane>>5)*8 .. +8]
// [4MB, +64KB)   sqpart[16][1024] f32
// then hp / hn / flags (1024 ints each)

// ---------------- fused prep: fp16 swizzle + sq partials + init ----------------

__global__ __launch_bounds__(256) void prep_kernel(const float* __restrict__ F,
                                                   _Float16* __restrict__ Fh,
                                                   float* __restrict__ sqpart,
                                                   int* __restrict__ hp,
                                                   int* __restrict__ hn,
                                                   int* __restrict__ flags) {
    __shared__ _Float16 slab[64][136];   // 64 rows x 128 cols, +8 pad
    __shared__ float part[64];

    const int b = blockIdx.x;            // 256 blocks
    const int i = b >> 4;                // 64-row group
    const int kseg = b & 15;             // 128-col segment
    const int t = threadIdx.x;
    const int lane = t & 63;
    const int w = t >> 6;

    const int idx = b * 256 + t;
    if (idx < 1024) {
        hp[idx] = 0;                     // 0.0f bits; real dists are > 0
        hn[idx] = 0x7F800000;            // +inf
        flags[idx] = 0;
    }

#pragma unroll
    for (int q = 0; q < 8; ++q) {
        const int rl = q * 8 + (t >> 5);
        const int c4 = (t & 31) * 4;
        const float4 v = *(const float4*)(F + (size_t)(i * 64 + rl) * D_SZ +
                                          kseg * 128 + c4);
        float s = v.x * v.x + v.y * v.y + v.z * v.z + v.w * v.w;
#pragma unroll
        for (int mask = 1; mask < 32; mask <<= 1) s += __shfl_xor(s, mask);
        if ((t & 31) == 0) part[rl] = s;
        H4 p;
        p.h[0] = (_Float16)v.x; p.h[1] = (_Float16)v.y;
        p.h[2] = (_Float16)v.z; p.h[3] = (_Float16)v.w;
        *(uint2*)&slab[rl][c4] = p.u;
    }
    __syncthreads();

    if (t < 64) sqpart[kseg * 1024 + i * 64 + t] = part[t];

#pragma unroll
    for (int q2 = 0; q2 < 4; ++q2) {
        const int u = w * 4 + q2;
        const int kb = u >> 1;
        const int rg = u & 1;
        const uint4 d = *(const uint4*)&slab[rg * 32 + (lane & 31)]
                                          [kb * 16 + (lane >> 5) * 8];
        const size_t g = (size_t)((i * 128 + kseg * 8 + kb) * 2 + rg);
        *(uint4*)((char*)Fh + g * 1024 + (size_t)lane * 16) = d;
    }
}

// ---------------- dist: reg-direct fp16 MFMA, 64x32 tiles, 512 blocks --------
// No LDS in the main loop (only 32KB combine area) -> 2 blocks/CU, 2 waves/SIMD,
// waves fully independent. Ping-pong depth-2 register pipeline (48 VGPR);
// compiler's counted vmcnt before first use + TLP hides L2 latency.
// Loads go through the plain L1/L2 path (~60 B/cy/CU) instead of the
// global_load_lds DMA engine (~20 B/cy/CU, the R8/R9 ceiling).

__global__ __launch_bounds__(256, 2) void dist_f16_kernel(
    const _Float16* __restrict__ Fh, const int* __restrict__ labels,
    const float* __restrict__ sqpart, int* __restrict__ hp,
    int* __restrict__ hn, int* __restrict__ flags) {
    __shared__ __align__(16) char cb[32768];   // combine area only
    __shared__ int labR[64], labC[32];
    __shared__ float sqR[64], sqC[32];

    const int t = threadIdx.x;
    const int lane = t & 63;
    const int w = t >> 6;   // wave id = K-quarter

    const int xcd = blockIdx.x & 7;
    const int cidx = blockIdx.x >> 3;          // 0..63
    const int bi = (xcd >> 1) * 4 + (cidx >> 4);   // 0..15 (64-row group)
    const int bj = (xcd & 1) * 16 + (cidx & 15);   // 0..31 (32-col group)
    const int rowBase = bi * 64, colBase = bj * 32;

    if (t < 64) {
        const int row = rowBase + t;
        float s = 0.f;
#pragma unroll
        for (int p = 0; p < 16; ++p) s += sqpart[p * 1024 + row];
        sqR[t] = s;
        labR[t] = labels[row];
    } else if (t < 96) {
        const int e = t - 64;
        const int row = colBase + e;
        float s = 0.f;
#pragma unroll
        for (int p = 0; p < 16; ++p) s += sqpart[p * 1024 + row];
        sqC[e] = s;
        labC[e] = labels[row];
    }
    __syncthreads();

    const char* __restrict__ FhB = (const char*)Fh;
    // Per-lane base pointers; substep s advances by 2048B (2 granules per kb16).
    const char* pA0 = FhB + (size_t)((bi * 128 + w * 32) * 2) * 1024 + (size_t)lane * 16;
    const char* pB0 = FhB + (size_t)(((bj >> 1) * 128 + w * 32) * 2 + (bj & 1)) * 1024 +
                      (size_t)lane * 16;

    f32x16 acc[2];
#pragma unroll
    for (int a = 0; a < 2; ++a)
#pragma unroll
        for (int e = 0; e < 16; ++e) acc[a][e] = 0.f;

    // One K=16 substep: 3 x global_load_dwordx4 straight into MFMA operands.
    auto LOADREG = [&](int s, uint4* r) {
        const size_t off = (size_t)s * 2048;
        r[0] = *(const uint4*)(pA0 + off);
        r[1] = *(const uint4*)(pA0 + off + 1024);
        r[2] = *(const uint4*)(pB0 + off);
    };
    auto MFMA2 = [&](const uint4* r) {
        FragU a0, a1, v0;
        a0.u = r[0];
        a1.u = r[1];
        v0.u = r[2];
        acc[0] = __builtin_amdgcn_mfma_f32_32x32x16_f16(a0.v, v0.v, acc[0], 0, 0, 0);
        acc[1] = __builtin_amdgcn_mfma_f32_32x32x16_f16(a1.v, v0.v, acc[1], 0, 0, 0);
    };

    uint4 ra[3], rb[3];
    LOADREG(0, ra);
#pragma unroll
    for (int s = 0; s < 32; s += 2) {
        LOADREG(s + 1, rb);          // issue next while ra is in flight/consumed
        MFMA2(ra);
        if (s + 2 < 32) LOADREG(s + 2, ra);
        MFMA2(rb);
    }

    __syncthreads();

    // Combine the 4 K-partials through LDS (32KB).
#pragma unroll
    for (int fr = 0; fr < 2; ++fr)
#pragma unroll
        for (int g = 0; g < 4; ++g) {
            float4 v;
            v.x = acc[fr][g * 4 + 0];
            v.y = acc[fr][g * 4 + 1];
            v.z = acc[fr][g * 4 + 2];
            v.w = acc[fr][g * 4 + 3];
            *(float4*)(cb + (size_t)(w * 8192) +
                       (size_t)((fr * 4 + g) * 64 + lane) * 16) = v;
        }
    __syncthreads();

    // Waves 0,1 own frag fr = w: sum 4 partials, then epilogue.
    if (w < 2) {
        const int fr = w;
        float cS[16];
#pragma unroll
        for (int e = 0; e < 16; ++e) cS[e] = 0.f;
#pragma unroll
        for (int wp = 0; wp < 4; ++wp)
#pragma unroll
            for (int g = 0; g < 4; ++g) {
                float4 v = *(const float4*)(cb + (size_t)(wp * 8192) +
                                            (size_t)((fr * 4 + g) * 64 + lane) * 16);
                cS[g * 4 + 0] += v.x;
                cS[g * 4 + 1] += v.y;
                cS[g * 4 + 2] += v.z;
                cS[g * 4 + 3] += v.w;
            }

        const float BIG = 1e38f;
        const int h = lane >> 5;
        const int colL = lane & 31;
        const int j = colBase + colL;
        const int lj = labC[colL];
        const float sqj = sqC[colL];
#pragma unroll
        for (int k = 0; k < 16; ++k) {
            const int rowL = fr * 32 + (k & 3) + 8 * (k >> 2) + 4 * h;
            const int i = rowBase + rowL;
            const float d2 = sqR[rowL] + sqj - 2.f * cS[k];
            const float d = sqrtf(fmaxf(d2, 1e-12f));
            const bool eq = (labR[rowL] == lj);
            const bool isPos = eq && (i != j);
            float pv = isPos ? d : -BIG;
            float nv = eq ? BIG : d;
            int pf = (isPos ? 1 : 0) | (eq ? 0 : 2);
#pragma unroll
            for (int mask = 1; mask < 32; mask <<= 1) {
                pv = fmaxf(pv, __shfl_xor(pv, mask));
                nv = fminf(nv, __shfl_xor(nv, mask));
                pf |= __shfl_xor(pf, mask);
            }
            if (colL == 0) {
                if (pf & 1) atomicMax(&hp[i], __float_as_int(pv));
                if (pf & 2) atomicMin(&hn[i], __float_as_int(nv));
                if (pf) atomicOr(&flags[i], pf);
            }
        }
    }
}

// ---------------- final ----------------

__global__ __launch_bounds__(1024) void final_kernel(const int* __restrict__ hp,
                                                     const int* __restrict__ hn,
                                                     const int* __restrict__ flags,
                                                     float* __restrict__ out) {
    __shared__ float ssum[16];
    __shared__ int svalid[16], sact[16];
    const int t = threadIdx.x;
    const float hpv = __int_as_float(hp[t]);
    const float hnv = __int_as_float(hn[t]);
    const int f = flags[t];
    const bool valid = (f == 3);
    float pr = fmaxf(hpv - hnv + MARGIN, 0.f);
    if (!valid) pr = 0.f;
    int act = (valid && pr > 0.f) ? 1 : 0;
    int vld = valid ? 1 : 0;
    float s = pr;
    for (int off = 32; off; off >>= 1) {
        s += __shfl_down(s, off);
        act += __shfl_down(act, off);
        vld += __shfl_down(vld, off);
    }
    if ((t & 63) == 0) {
        ssum[t >> 6] = s;
        svalid[t >> 6] = vld;
        sact[t >> 6] = act;
    }
    __syncthreads();
    if (t == 0) {
        float tot = 0.f;
        int nv = 0, na = 0;
#pragma unroll
        for (int i = 0; i < 16; ++i) {
            tot += ssum[i];
            nv += svalid[i];
            na += sact[i];
        }
        out[0] = tot / (float)(nv > 1 ? nv : 1);
        out[1] = (float)na;
    }
}

// ---------------- fallback path: fp32 vector ----------------

#define BM 64
#define BN 64
#define BK 32

__global__ __launch_bounds__(256) void sq_kernel(const float* __restrict__ F,
                                                 float* __restrict__ sq) {
    int row = blockIdx.x;
    const float4* r4 = (const float4*)(F + (size_t)row * D_SZ);
    int t = threadIdx.x;
    float s = 0.f;
#pragma unroll
    for (int q = 0; q < 2; ++q) {
        float4 v = r4[t + q * 256];
        s += v.x * v.x + v.y * v.y + v.z * v.z + v.w * v.w;
    }
    for (int off = 32; off; off >>= 1) s += __shfl_down(s, off);
    __shared__ float wsum[4];
    if ((t & 63) == 0) wsum[t >> 6] = s;
    __syncthreads();
    if (t == 0) sq[row] = wsum[0] + wsum[1] + wsum[2] + wsum[3];
}

__global__ __launch_bounds__(256) void init_kernel(int* __restrict__ hp,
                                                   int* __restrict__ hn,
                                                   int* __restrict__ flags) {
    int i = blockIdx.x * 256 + threadIdx.x;
    hp[i] = 0;
    hn[i] = 0x7F800000;
    flags[i] = 0;
}

__global__ __launch_bounds__(256) void dist_f32_kernel(
    const float* __restrict__ F, const int* __restrict__ labels,
    const float* __restrict__ sq, int* __restrict__ hp, int* __restrict__ hn,
    int* __restrict__ flags) {
    __shared__ float As[BK][BM];
    __shared__ float Bs[BK][BN];
    __shared__ int labR[BM], labC[BN];
    __shared__ float sqR[BM], sqC[BN];

    const int rowBase = blockIdx.y * BM;
    const int colBase = blockIdx.x * BN;
    const int t = threadIdx.x;
    const int tx = t & 15;
    const int ty = t >> 4;

    if (t < 64) {
        labR[t] = labels[rowBase + t];
        sqR[t] = sq[rowBase + t];
    } else if (t < 128) {
        int u = t - 64;
        labC[u] = labels[colBase + u];
        sqC[u] = sq[colBase + u];
    }

    float acc[4][4] = {{0.f}};
    const int m = t & 63;
    const int q = t >> 6;
    const float* aRow = F + (size_t)(rowBase + m) * D_SZ + q * 8;
    const float* bRow = F + (size_t)(colBase + m) * D_SZ + q * 8;

    for (int k0 = 0; k0 < D_SZ; k0 += BK) {
        float4 a0 = *(const float4*)(aRow + k0);
        float4 a1 = *(const float4*)(aRow + k0 + 4);
        float4 b0 = *(const float4*)(bRow + k0);
        float4 b1 = *(const float4*)(bRow + k0 + 4);
        __syncthreads();
        int kb = q * 8;
        As[kb + 0][m] = a0.x; As[kb + 1][m] = a0.y;
        As[kb + 2][m] = a0.z; As[kb + 3][m] = a0.w;
        As[kb + 4][m] = a1.x; As[kb + 5][m] = a1.y;
        As[kb + 6][m] = a1.z; As[kb + 7][m] = a1.w;
        Bs[kb + 0][m] = b0.x; Bs[kb + 1][m] = b0.y;
        Bs[kb + 2][m] = b0.z; Bs[kb + 3][m] = b0.w;
        Bs[kb + 4][m] = b1.x; Bs[kb + 5][m] = b1.y;
        Bs[kb + 6][m] = b1.z; Bs[kb + 7][m] = b1.w;
        __syncthreads();
#pragma unroll
        for (int kk = 0; kk < BK; ++kk) {
            float4 a = *(const float4*)&As[kk][ty * 4];
            float4 b = *(const float4*)&Bs[kk][tx * 4];
            acc[0][0] += a.x * b.x; acc[0][1] += a.x * b.y;
            acc[0][2] += a.x * b.z; acc[0][3] += a.x * b.w;
            acc[1][0] += a.y * b.x; acc[1][1] += a.y * b.y;
            acc[1][2] += a.y * b.z; acc[1][3] += a.y * b.w;
            acc[2][0] += a.z * b.x; acc[2][1] += a.z * b.y;
            acc[2][2] += a.z * b.z; acc[2][3] += a.z * b.w;
            acc[3][0] += a.w * b.x; acc[3][1] += a.w * b.y;
            acc[3][2] += a.w * b.z; acc[3][3] += a.w * b.w;
        }
    }

    float mp[4], mn[4];
    int pf[4];
#pragma unroll
    for (int rr = 0; rr < 4; ++rr) {
        const int i = rowBase + ty * 4 + rr;
        const int li = labR[ty * 4 + rr];
        const float si = sqR[ty * 4 + rr];
        mp[rr] = -3.4e38f;
        mn[rr] = 3.4e38f;
        pf[rr] = 0;
#pragma unroll
        for (int c = 0; c < 4; ++c) {
            const int j = colBase + tx * 4 + c;
            const float d2 = si + sqC[tx * 4 + c] - 2.f * acc[rr][c];
            const float dist = sqrtf(fmaxf(d2, 1e-12f));
            const bool eq = (li == labC[tx * 4 + c]);
            if (eq && (i != j)) {
                mp[rr] = fmaxf(mp[rr], dist);
                pf[rr] |= 1;
            }
            if (!eq) {
                mn[rr] = fminf(mn[rr], dist);
                pf[rr] |= 2;
            }
        }
    }
#pragma unroll
    for (int mask = 1; mask < 16; mask <<= 1)
#pragma unroll
        for (int rr = 0; rr < 4; ++rr) {
            mp[rr] = fmaxf(mp[rr], __shfl_xor(mp[rr], mask));
            mn[rr] = fminf(mn[rr], __shfl_xor(mn[rr], mask));
            pf[rr] |= __shfl_xor(pf[rr], mask);
        }
    if (tx == 0) {
#pragma unroll
        for (int rr = 0; rr < 4; ++rr) {
            const int i = rowBase + ty * 4 + rr;
            if (pf[rr] & 1) atomicMax(&hp[i], __float_as_int(mp[rr]));
            if (pf[rr] & 2) atomicMin(&hn[i], __float_as_int(mn[rr]));
            if (pf[rr]) atomicOr(&flags[i], pf[rr]);
        }
    }
}

// ---------------- launch ----------------

extern "C" void kernel_launch(void* const* d_in, const int* in_sizes, int n_in,
                              void* d_out, int out_size, void* d_ws, size_t ws_size,
                              hipStream_t stream) {
    const float* F = (const float*)d_in[0];
    const int* labels = (const int*)d_in[1];
    float* out = (float*)d_out;
    char* ws = (char*)d_ws;

    const size_t FH = (size_t)B_SZ * D_SZ * 2;         // 4MB fp16 swizzled
    const size_t SQP = 16 * 1024 * sizeof(float);      // 64KB
    const size_t need = FH + SQP + 12 * 1024;

    if (ws_size >= need) {
        _Float16* Fh = (_Float16*)ws;
        float* sqpart = (float*)(ws + FH);
        char* tail = ws + FH + SQP;
        int* hp = (int*)tail;
        int* hn = (int*)(tail + 4096);
        int* flags = (int*)(tail + 8192);

        prep_kernel<<<256, 256, 0, stream>>>(F, Fh, sqpart, hp, hn, flags);
        dist_f16_kernel<<<512, 256, 0, stream>>>(Fh, labels, sqpart, hp, hn, flags);
        final_kernel<<<1, 1024, 0, stream>>>(hp, hn, flags, out);
    } else {
        float* sq = (float*)ws;
        int* hp = (int*)(ws + 4096);
        int* hn = (int*)(ws + 8192);
        int* flags = (int*)(ws + 12288);

        sq_kernel<<<B_SZ, 256, 0, stream>>>(F, sq);
        init_kernel<<<B_SZ / 256, 256, 0, stream>>>(hp, hn, flags);
        dim3 grid(B_SZ / BN, B_SZ / BM);
        dist_f32_kernel<<<grid, 256, 0, stream>>>(F, labels, sq, hp, hn, flags);
        final_kernel<<<1, 1024, 0, stream>>>(hp, hn, flags, out);
    }
}